// Round 13
// baseline (770.795 us; speedup 1.0000x reference)
//
#include <hip/hip_runtime.h>

#define D 64
#define F 128
#define NBMAX 256

typedef unsigned int uint;
typedef unsigned short ushort;
typedef short s16x8 __attribute__((ext_vector_type(8)));
typedef float f32x4 __attribute__((ext_vector_type(4)));

__device__ __forceinline__ float bf16lo(uint u) { return __uint_as_float(u << 16); }
__device__ __forceinline__ float bf16hi(uint u) { return __uint_as_float(u & 0xFFFF0000u); }
__device__ __forceinline__ ushort f2bf16(float f) {
    uint u = __float_as_uint(f);
    u += 0x7FFFu + ((u >> 16) & 1u);   // RNE
    return (ushort)(u >> 16);
}
__device__ __forceinline__ uint pk2bf(float lo, float hi) {
    return (uint)f2bf16(lo) | ((uint)f2bf16(hi) << 16);
}
__device__ __forceinline__ float rdlane(float v, int l) {
    return __uint_as_float(__builtin_amdgcn_readlane(__float_as_uint(v), l));
}
__device__ __forceinline__ int ceil16(int x) { return (x + 15) & ~15; }

// ================= bucketed CSR build (N <= 65536) =================

__global__ __launch_bounds__(256) void bucket_hist(const int* __restrict__ dst,
                                                   int* __restrict__ gb, int E, int nb) {
    __shared__ int h[NBMAX];
    for (int t = threadIdx.x; t < nb; t += 256) h[t] = 0;
    __syncthreads();
    int start = blockIdx.x * 4096;
    int end   = start + 4096 < E ? start + 4096 : E;
    for (int i = start + threadIdx.x; i < end; i += 256)
        atomicAdd(&h[dst[i] >> 8], 1);
    __syncthreads();
    for (int t = threadIdx.x; t < nb; t += 256)
        if (h[t]) atomicAdd(&gb[t], h[t]);
}

__global__ void bucket_scan(const int* __restrict__ gb, int* __restrict__ gboff,
                            int* __restrict__ gcur, int nb) {
    if (threadIdx.x == 0) {
        int s = 0;
        for (int b = 0; b < nb; ++b) { gboff[b] = s; gcur[b] = s; s += gb[b]; }
        gboff[nb] = s;
    }
}

__global__ __launch_bounds__(256) void bucket_scatter(const int* __restrict__ src,
                                                      const int* __restrict__ dst,
                                                      int* __restrict__ gcur,
                                                      int* __restrict__ packed, int E, int nb) {
    __shared__ int h[NBMAX], base[NBMAX], lcur[NBMAX];
    for (int t = threadIdx.x; t < nb; t += 256) h[t] = 0;
    __syncthreads();
    int start = blockIdx.x * 4096;
    int end   = start + 4096 < E ? start + 4096 : E;
    for (int i = start + threadIdx.x; i < end; i += 256)
        atomicAdd(&h[dst[i] >> 8], 1);
    __syncthreads();
    for (int t = threadIdx.x; t < nb; t += 256) {
        base[t] = h[t] ? atomicAdd(&gcur[t], h[t]) : 0;
        lcur[t] = 0;
    }
    __syncthreads();
    for (int i = start + threadIdx.x; i < end; i += 256) {
        int d = dst[i];
        int b = d >> 8;
        int pos = base[b] + atomicAdd(&lcur[b], 1);
        packed[pos] = (src[i] << 8) | (d & 255);
    }
}

__global__ __launch_bounds__(256) void bucket_deg(const int* __restrict__ gboff,
                                                  const int* __restrict__ packed,
                                                  int* __restrict__ deg, int N) {
    __shared__ int h[NBMAX];
    int b = blockIdx.x;
    h[threadIdx.x] = 0;
    __syncthreads();
    int st = gboff[b], en = gboff[b + 1];
    for (int i = st + threadIdx.x; i < en; i += 256)
        atomicAdd(&h[packed[i] & 255], 1);
    __syncthreads();
    int node = (b << 8) + threadIdx.x;
    if (node < N) deg[node] = h[threadIdx.x];
}

__global__ __launch_bounds__(256) void bucket_cntlo(const int* __restrict__ gboff,
                                                    const int* __restrict__ packed,
                                                    int* __restrict__ cnt_lo, int N, int NH) {
    __shared__ int h[NBMAX];
    int b = blockIdx.x;
    h[threadIdx.x] = 0;
    __syncthreads();
    int st = gboff[b], en = gboff[b + 1];
    for (int i = st + threadIdx.x; i < en; i += 256) {
        int p = packed[i];
        if ((p >> 8) < NH) atomicAdd(&h[p & 255], 1);
    }
    __syncthreads();
    int node = (b << 8) + threadIdx.x;
    if (node < N) cnt_lo[node] = h[threadIdx.x];
}

// two-cursor fill: lo-src neighbors first, then hi-src (sections padded to 16)
__global__ __launch_bounds__(256) void bucket_fill(const int* __restrict__ gboff,
                                                   const int* __restrict__ packed,
                                                   const int* __restrict__ row_ptr,
                                                   const int* __restrict__ cnt_lo,
                                                   int* __restrict__ col, int N, int NH) {
    __shared__ int lcur_lo[NBMAX], lcur_hi[NBMAX];
    int b = blockIdx.x;
    int node = (b << 8) + threadIdx.x;
    lcur_lo[threadIdx.x] = (node < N) ? row_ptr[node] : 0;
    lcur_hi[threadIdx.x] = (node < N) ? row_ptr[node] + ceil16(cnt_lo[node]) : 0;
    __syncthreads();
    int st = gboff[b], en = gboff[b + 1];
    for (int i = st + threadIdx.x; i < en; i += 256) {
        int p = packed[i];
        int s = p >> 8;
        int pos = (s < NH) ? atomicAdd(&lcur_lo[p & 255], 1)
                           : atomicAdd(&lcur_hi[p & 255], 1);
        col[pos] = s;
    }
}

// ================= fallback CSR build (N > 65536) =================

__global__ void count_deg_kernel(const int* __restrict__ dst, int* __restrict__ deg, int E) {
    int i = blockIdx.x * blockDim.x + threadIdx.x;
    if (i < E) atomicAdd(&deg[dst[i]], 1);
}

__global__ void cntlo_global_kernel(const int* __restrict__ src, const int* __restrict__ dst,
                                    int* __restrict__ cnt_lo, int E, int NH) {
    int i = blockIdx.x * blockDim.x + threadIdx.x;
    if (i < E && src[i] < NH) atomicAdd(&cnt_lo[dst[i]], 1);
}

__global__ void mkcur_kernel(const int* __restrict__ row_ptr, const int* __restrict__ cnt_lo,
                             int* __restrict__ cur_lo, int* __restrict__ cur_hi, int N) {
    int v = blockIdx.x * blockDim.x + threadIdx.x;
    if (v < N) { cur_lo[v] = row_ptr[v]; cur_hi[v] = row_ptr[v] + ceil16(cnt_lo[v]); }
}

__global__ void fill2_kernel(const int* __restrict__ src, const int* __restrict__ dst,
                             int* __restrict__ cur_lo, int* __restrict__ cur_hi,
                             int* __restrict__ col, int E, int NH) {
    int i = blockIdx.x * blockDim.x + threadIdx.x;
    if (i < E) {
        int d_ = dst[i];
        int s = src[i];
        int pos = (s < NH) ? atomicAdd(&cur_lo[d_], 1) : atomicAdd(&cur_hi[d_], 1);
        col[pos] = s;
    }
}

// ================= row_ptr scan: padded = ceil16(cnt_lo) + ceil16(deg-cnt_lo) =================

__global__ __launch_bounds__(1024) void scan_kernel(const int* __restrict__ deg,
                                                    const int* __restrict__ cnt_lo,
                                                    int* __restrict__ row_ptr, int n) {
    __shared__ int wsum[16];
    int lane = threadIdx.x & 63;
    int wid  = threadIdx.x >> 6;
    int carry = 0;
    const int CH = 4096;
    for (int base = 0; base < n; base += CH) {
        int i0 = base + (int)threadIdx.x * 4;
        int v0 = 0, v1 = 0, v2 = 0, v3 = 0;
        if (i0     < n) { int c = cnt_lo[i0];     v0 = ceil16(c) + ceil16(deg[i0]     - c); }
        if (i0 + 1 < n) { int c = cnt_lo[i0 + 1]; v1 = ceil16(c) + ceil16(deg[i0 + 1] - c); }
        if (i0 + 2 < n) { int c = cnt_lo[i0 + 2]; v2 = ceil16(c) + ceil16(deg[i0 + 2] - c); }
        if (i0 + 3 < n) { int c = cnt_lo[i0 + 3]; v3 = ceil16(c) + ceil16(deg[i0 + 3] - c); }
        int p0 = v0, p1 = p0 + v1, p2 = p1 + v2, p3 = p2 + v3;
        int tsum = p3;
        int s = tsum;
        #pragma unroll
        for (int off = 1; off < 64; off <<= 1) {
            int t = __shfl_up(s, off);
            if (lane >= off) s += t;
        }
        if (lane == 63) wsum[wid] = s;
        __syncthreads();
        int wbase = 0, chunk_total = 0;
        #pragma unroll
        for (int w = 0; w < 16; ++w) {
            int t = wsum[w];
            chunk_total += t;
            if (w < wid) wbase += t;
        }
        __syncthreads();
        int ex = carry + wbase + (s - tsum);
        if (i0     < n) row_ptr[i0 + 1] = ex + p0;
        if (i0 + 1 < n) row_ptr[i0 + 2] = ex + p1;
        if (i0 + 2 < n) row_ptr[i0 + 3] = ex + p2;
        if (i0 + 3 < n) row_ptr[i0 + 4] = ex + p3;
        carry += chunk_total;
    }
    if (threadIdx.x == 0) row_ptr[0] = 0;
}

// pad both sections' tails with the zero row N
__global__ void pad_kernel(const int* __restrict__ row_ptr, const int* __restrict__ deg,
                           const int* __restrict__ cnt_lo, int* __restrict__ col, int N) {
    int v = blockIdx.x * blockDim.x + threadIdx.x;
    if (v < N) {
        int rp = row_ptr[v];
        int cl = cnt_lo[v], ch = deg[v] - cl;
        int cl16 = ceil16(cl);
        for (int k = rp + cl; k < rp + cl16; ++k) col[k] = N;
        int hbase = rp + cl16;
        int ch16 = ceil16(ch);
        for (int k = hbase + ch; k < hbase + ch16; ++k) col[k] = N;
    }
}

// ================= Wx via MFMA (bf16 in, f32 acc) + fused emb1 init =================

__global__ __launch_bounds__(256) void wx_mfma_kernel(const float* __restrict__ x,
                                                      const float* __restrict__ W1,
                                                      const float* __restrict__ b1,
                                                      const float* __restrict__ b2,
                                                      float* __restrict__ Wx,
                                                      ushort* __restrict__ emb, int N) {
    int lane = threadIdx.x & 63;
    int wv = blockIdx.x * 4 + (threadIdx.x >> 6);
    int nwaves = gridDim.x * 4;
    int r16 = lane & 15;
    int kg  = lane >> 4;

    s16x8 bf[4][4];
    #pragma unroll
    for (int nt = 0; nt < 4; ++nt) {
        const float* wrow = W1 + (size_t)(nt * 16 + r16) * F;
        #pragma unroll
        for (int ks = 0; ks < 4; ++ks) {
            const float4* p = reinterpret_cast<const float4*>(wrow + ks * 32 + kg * 8);
            float4 f0 = p[0], f1 = p[1];
            union { s16x8 v; uint u[4]; } t;
            t.u[0] = pk2bf(f0.x, f0.y); t.u[1] = pk2bf(f0.z, f0.w);
            t.u[2] = pk2bf(f1.x, f1.y); t.u[3] = pk2bf(f1.z, f1.w);
            bf[nt][ks] = t.v;
        }
    }
    float b1v[4], b2v[4];
    #pragma unroll
    for (int nt = 0; nt < 4; ++nt) {
        b1v[nt] = b1[nt * 16 + r16];
        b2v[nt] = b2[nt * 16 + r16];
    }

    int ntiles = (N + 15) >> 4;
    for (int tile = wv; tile < ntiles; tile += nwaves) {
        int row0 = tile << 4;
        int arow = row0 + r16;
        if (arow >= N) arow = N - 1;
        s16x8 af[4];
        #pragma unroll
        for (int ks = 0; ks < 4; ++ks) {
            const float4* p = reinterpret_cast<const float4*>(x + (size_t)arow * F + ks * 32 + kg * 8);
            float4 f0 = p[0], f1 = p[1];
            union { s16x8 v; uint u[4]; } t;
            t.u[0] = pk2bf(f0.x, f0.y); t.u[1] = pk2bf(f0.z, f0.w);
            t.u[2] = pk2bf(f1.x, f1.y); t.u[3] = pk2bf(f1.z, f1.w);
            af[ks] = t.v;
        }
        #pragma unroll
        for (int nt = 0; nt < 4; ++nt) {
            f32x4 acc = {0.f, 0.f, 0.f, 0.f};
            #pragma unroll
            for (int ks = 0; ks < 4; ++ks)
                acc = __builtin_amdgcn_mfma_f32_16x16x32_bf16(af[ks], bf[nt][ks], acc, 0, 0, 0);
            int outd = nt * 16 + r16;
            #pragma unroll
            for (int r = 0; r < 4; ++r) {
                int node = row0 + kg * 4 + r;
                if (node < N) {
                    float wxv = acc[r] + b1v[nt];
                    Wx[(size_t)node * D + outd] = wxv;
                    float e = wxv + b2v[nt];
                    emb[(size_t)node * D + outd] = f2bf16(e > 0.f ? e : 0.f);
                }
            }
        }
    }
}

// ================= gather macro body (R12's proven pipeline) =================
// lane = 8*g + s; accumulates 8 dims [8s..8s+7] ... after xor-reduce lane holds
// dims [8*(lane&7) .. +7]. Section [st,en) is a multiple of 16.

#define GATHER_SECTION(pin_, st_, en_)                                              \
    if ((st_) < (en_)) {                                                            \
        int u0 = col[(st_) + g], u1 = col[(st_) + 8 + g];                           \
        uint4 q0 = reinterpret_cast<const uint4*>((pin_) + ((size_t)u0 << 6))[s];   \
        uint4 q1 = reinterpret_cast<const uint4*>((pin_) + ((size_t)u1 << 6))[s];   \
        int k = (st_) + 16;                                                         \
        int n0 = N, n1 = N;                                                         \
        if (k < (en_)) { n0 = col[k + g]; n1 = col[k + 8 + g]; }                    \
        for (; k < (en_); k += 16) {                                                \
            uint4 p0 = reinterpret_cast<const uint4*>((pin_) + ((size_t)n0 << 6))[s]; \
            uint4 p1 = reinterpret_cast<const uint4*>((pin_) + ((size_t)n1 << 6))[s]; \
            int k2 = k + 16;                                                        \
            int m0 = N, m1 = N;                                                     \
            if (k2 < (en_)) { m0 = col[k2 + g]; m1 = col[k2 + 8 + g]; }             \
            a0 += bf16lo(q0.x); a1 += bf16hi(q0.x);                                 \
            a2 += bf16lo(q0.y); a3 += bf16hi(q0.y);                                 \
            a4 += bf16lo(q0.z); a5 += bf16hi(q0.z);                                 \
            a6 += bf16lo(q0.w); a7 += bf16hi(q0.w);                                 \
            a0 += bf16lo(q1.x); a1 += bf16hi(q1.x);                                 \
            a2 += bf16lo(q1.y); a3 += bf16hi(q1.y);                                 \
            a4 += bf16lo(q1.z); a5 += bf16hi(q1.z);                                 \
            a6 += bf16lo(q1.w); a7 += bf16hi(q1.w);                                 \
            q0 = p0; q1 = p1; n0 = m0; n1 = m1;                                     \
        }                                                                           \
        a0 += bf16lo(q0.x); a1 += bf16hi(q0.x);                                     \
        a2 += bf16lo(q0.y); a3 += bf16hi(q0.y);                                     \
        a4 += bf16lo(q0.z); a5 += bf16hi(q0.z);                                     \
        a6 += bf16lo(q0.w); a7 += bf16hi(q0.w);                                     \
        a0 += bf16lo(q1.x); a1 += bf16hi(q1.x);                                     \
        a2 += bf16lo(q1.y); a3 += bf16hi(q1.y);                                     \
        a4 += bf16lo(q1.z); a5 += bf16hi(q1.z);                                     \
        a6 += bf16lo(q1.w); a7 += bf16hi(q1.w);                                     \
    }

#define XOR_REDUCE()                                                                \
    _Pragma("unroll")                                                               \
    for (int off = 8; off < 64; off <<= 1) {                                        \
        a0 += __shfl_xor(a0, off); a1 += __shfl_xor(a1, off);                       \
        a2 += __shfl_xor(a2, off); a3 += __shfl_xor(a3, off);                       \
        a4 += __shfl_xor(a4, off); a5 += __shfl_xor(a5, off);                       \
        a6 += __shfl_xor(a6, off); a7 += __shfl_xor(a7, off);                       \
    }

// ================= step phase A: lo-src gathers (3.2MB working set) -> f32 agg =================

__global__ __launch_bounds__(256) void gather_lo_kernel(const ushort* __restrict__ emb_in,
                                                        float* __restrict__ agg,
                                                        const int* __restrict__ row_ptr,
                                                        const int* __restrict__ col,
                                                        const int* __restrict__ cnt_lo, int N) {
    int t = threadIdx.x;
    int lane = t & 63, wid = t >> 6;
    int g = lane >> 3, s = lane & 7;
    int nw = gridDim.x * 4;
    for (int v = blockIdx.x * 4 + wid; v < N; v += nw) {
        int st = row_ptr[v];
        int en = st + ceil16(cnt_lo[v]);
        float a0 = 0.f, a1 = 0.f, a2 = 0.f, a3 = 0.f, a4 = 0.f, a5 = 0.f, a6 = 0.f, a7 = 0.f;
        GATHER_SECTION(emb_in, st, en)
        XOR_REDUCE()
        if (g == 0) {  // lanes 0..7 write dims [8s..8s+7]
            float* ap = agg + (size_t)v * D + s * 8;
            *reinterpret_cast<float4*>(ap)     = (float4){a0, a1, a2, a3};
            *reinterpret_cast<float4*>(ap + 4) = (float4){a4, a5, a6, a7};
        }
    }
}

// ================= step phase B: hi-src gathers + agg + matvec + store / LAST partials =================

template <bool LAST>
__global__ __launch_bounds__(256) void gather_hi_finish_kernel(const ushort* __restrict__ emb_in,
                                                               const float* __restrict__ agg,
                                                               ushort* __restrict__ emb_out,
                                                               const float* __restrict__ Wx,
                                                               const float* __restrict__ W2,
                                                               const float* __restrict__ b2,
                                                               const int* __restrict__ row_ptr,
                                                               const int* __restrict__ col,
                                                               const int* __restrict__ cnt_lo,
                                                               float* __restrict__ partial, int N) {
    __shared__ float w2t[D][D + 1];
    int t = threadIdx.x;
    #pragma unroll
    for (int i = t; i < D * D; i += 256) {
        int dd = i >> 6, kk = i & 63;
        w2t[kk][dd] = W2[i];
    }
    __syncthreads();
    int lane = t & 63, wid = t >> 6;
    float b2v = b2[lane];
    int g = lane >> 3, s = lane & 7;
    int nw = gridDim.x * 4;
    float sacc = 0.f;
    for (int v = blockIdx.x * 4 + wid; v < N; v += nw) {
        int rp = row_ptr[v];
        int st = rp + ceil16(cnt_lo[v]);
        int en = row_ptr[v + 1];
        float a0, a1, a2, a3, a4, a5, a6, a7;
        {
            const float* ap = agg + (size_t)v * D + s * 8;
            float4 p0 = *reinterpret_cast<const float4*>(ap);
            float4 p1 = *reinterpret_cast<const float4*>(ap + 4);
            a0 = p0.x; a1 = p0.y; a2 = p0.z; a3 = p0.w;
            a4 = p1.x; a5 = p1.y; a6 = p1.z; a7 = p1.w;
        }
        // hi-section gather adds into a0..a7 pre-reduce (each group partial), so
        // scale: agg already reduced; divide contribution evenly? No -- gather
        // accumulates per-group partials then xor-reduce would 8x the agg part.
        // Instead: gather into separate regs, reduce, then add agg.
        float h0 = 0.f, h1 = 0.f, h2 = 0.f, h3 = 0.f, h4 = 0.f, h5 = 0.f, h6 = 0.f, h7 = 0.f;
        {
            float b0 = a0, b1 = a1, b2_ = a2, b3 = a3, b4 = a4, b5 = a5, b6 = a6, b7 = a7;
            a0 = 0.f; a1 = 0.f; a2 = 0.f; a3 = 0.f; a4 = 0.f; a5 = 0.f; a6 = 0.f; a7 = 0.f;
            GATHER_SECTION(emb_in, st, en)
            XOR_REDUCE()
            h0 = b0; h1 = b1; h2 = b2_; h3 = b3; h4 = b4; h5 = b5; h6 = b6; h7 = b7;
        }
        a0 += h0; a1 += h1; a2 += h2; a3 += h3;
        a4 += h4; a5 += h5; a6 += h6; a7 += h7;

        float r = Wx[(size_t)v * D + lane] + b2v;
        #pragma unroll
        for (int kk = 0; kk < D; ++kk) {
            float av;
            switch (kk & 7) {
                case 0: av = rdlane(a0, kk >> 3); break;
                case 1: av = rdlane(a1, kk >> 3); break;
                case 2: av = rdlane(a2, kk >> 3); break;
                case 3: av = rdlane(a3, kk >> 3); break;
                case 4: av = rdlane(a4, kk >> 3); break;
                case 5: av = rdlane(a5, kk >> 3); break;
                case 6: av = rdlane(a6, kk >> 3); break;
                default: av = rdlane(a7, kk >> 3); break;
            }
            r += av * w2t[kk][lane];
        }
        float rr = r > 0.f ? r : 0.f;
        if (LAST) {
            sacc += __uint_as_float((uint)f2bf16(rr) << 16);
        } else {
            emb_out[(size_t)v * D + lane] = f2bf16(rr);
        }
    }
    if (LAST) {
        __shared__ float red[256];
        red[t] = sacc;
        __syncthreads();
        if (t < 64) {
            float sum = red[t] + red[t + 64] + red[t + 128] + red[t + 192];
            partial[(size_t)blockIdx.x * 64 + t] = sum;
        }
    }
}

// sum per-block partials -> out
__global__ __launch_bounds__(256) void final_reduce_kernel(const float* __restrict__ partial,
                                                           float* __restrict__ out, int nblocks) {
    __shared__ float red[256];
    int t = threadIdx.x;
    int d = t & 63, q = t >> 6;
    float acc = 0.f;
    for (int b = q; b < nblocks; b += 4)
        acc += partial[(size_t)b * 64 + d];
    red[t] = acc;
    __syncthreads();
    if (t < 64)
        out[t] = red[t] + red[t + 64] + red[t + 128] + red[t + 192];
}

extern "C" void kernel_launch(void* const* d_in, const int* in_sizes, int n_in,
                              void* d_out, int out_size, void* d_ws, size_t ws_size,
                              hipStream_t stream) {
    const float* x    = (const float*)d_in[0];
    const float* W1   = (const float*)d_in[1];
    const float* b1   = (const float*)d_in[2];
    const float* W2   = (const float*)d_in[3];
    const float* b2   = (const float*)d_in[4];
    const int*   esrc = (const int*)d_in[5];
    const int*   edst = (const int*)d_in[6];
    int N = in_sizes[0] / F;
    int E = in_sizes[5];
    int NH = N >> 1;
    float* out = (float*)d_out;

    char* ws = (char*)d_ws;
    size_t off = 0;
    auto alloc = [&](size_t bytes) -> char* {
        char* p = ws + off;
        off += (bytes + 255) & ~(size_t)255;
        return p;
    };
    float*  Wx      = (float*)alloc((size_t)N * D * 4);
    ushort* embA    = (ushort*)alloc(((size_t)N + 1) * D * 2);
    ushort* embB    = (ushort*)alloc(((size_t)N + 1) * D * 2);
    float*  agg     = (float*)alloc((size_t)N * D * 4);
    int*    row_ptr = (int*)alloc(((size_t)N + 1) * 4);
    int*    deg     = (int*)alloc((size_t)N * 4);
    int*    cnt_lo  = (int*)alloc((size_t)N * 4);
    int*    col     = (int*)alloc(((size_t)E + 31 * (size_t)N) * 4);
    int*    packed  = (int*)alloc((size_t)E * 4);
    float*  partial = (float*)alloc((size_t)2048 * 64 * 4);
    int*    gb      = (int*)alloc((NBMAX + 1) * 4);
    int*    gboff   = (int*)alloc((NBMAX + 1) * 4);
    int*    gcur    = (int*)alloc((NBMAX + 1) * 4);
    int*    cur_lo  = (int*)alloc((size_t)N * 4);  // fallback only
    int*    cur_hi  = (int*)alloc((size_t)N * 4);  // fallback only

    hipMemsetAsync(embA + (size_t)N * D, 0, D * 2, stream);
    hipMemsetAsync(embB + (size_t)N * D, 0, D * 2, stream);

    int nb = ((N - 1) >> 8) + 1;
    int nchunks = (E + 4095) / 4096;
    if (N <= 65536) {
        hipMemsetAsync(gb, 0, (size_t)nb * 4, stream);
        bucket_hist<<<nchunks, 256, 0, stream>>>(edst, gb, E, nb);
        bucket_scan<<<1, 64, 0, stream>>>(gb, gboff, gcur, nb);
        bucket_scatter<<<nchunks, 256, 0, stream>>>(esrc, edst, gcur, packed, E, nb);
        bucket_deg<<<nb, 256, 0, stream>>>(gboff, packed, deg, N);
        bucket_cntlo<<<nb, 256, 0, stream>>>(gboff, packed, cnt_lo, N, NH);
        scan_kernel<<<1, 1024, 0, stream>>>(deg, cnt_lo, row_ptr, N);
        bucket_fill<<<nb, 256, 0, stream>>>(gboff, packed, row_ptr, cnt_lo, col, N, NH);
    } else {
        hipMemsetAsync(deg, 0, (size_t)N * 4, stream);
        hipMemsetAsync(cnt_lo, 0, (size_t)N * 4, stream);
        count_deg_kernel<<<(E + 255) / 256, 256, 0, stream>>>(edst, deg, E);
        cntlo_global_kernel<<<(E + 255) / 256, 256, 0, stream>>>(esrc, edst, cnt_lo, E, NH);
        scan_kernel<<<1, 1024, 0, stream>>>(deg, cnt_lo, row_ptr, N);
        mkcur_kernel<<<(N + 255) / 256, 256, 0, stream>>>(row_ptr, cnt_lo, cur_lo, cur_hi, N);
        fill2_kernel<<<(E + 255) / 256, 256, 0, stream>>>(esrc, edst, cur_lo, cur_hi, col, E, NH);
    }
    pad_kernel<<<(N + 255) / 256, 256, 0, stream>>>(row_ptr, deg, cnt_lo, col, N);

    wx_mfma_kernel<<<1024, 256, 0, stream>>>(x, W1, b1, b2, Wx, embA, N);

    ushort* pin = embA;
    ushort* pout = embB;
    for (int t = 1; t < 9; ++t) {  // steps 2..9
        gather_lo_kernel<<<2048, 256, 0, stream>>>(pin, agg, row_ptr, col, cnt_lo, N);
        gather_hi_finish_kernel<false><<<2048, 256, 0, stream>>>(pin, agg, pout, Wx, W2, b2,
                                                                 row_ptr, col, cnt_lo,
                                                                 partial, N);
        ushort* tmp = pin; pin = pout; pout = tmp;
    }
    // step 10: fused reduce via per-block partials
    gather_lo_kernel<<<2048, 256, 0, stream>>>(pin, agg, row_ptr, col, cnt_lo, N);
    gather_hi_finish_kernel<true><<<2048, 256, 0, stream>>>(pin, agg, pout, Wx, W2, b2,
                                                            row_ptr, col, cnt_lo,
                                                            partial, N);
    final_reduce_kernel<<<1, 256, 0, stream>>>(partial, out, 2048);
}